// Round 10
// baseline (1848.983 us; speedup 1.0000x reference)
//
#include <hip/hip_runtime.h>
#include <stdint.h>
#include <stddef.h>

#define VOCAB  128
#define HIDDEN 1024
#define BATCH  64
#define SEQ    512

#define NGROUP 4      // batch groups
#define BG     16     // batches per group
#define NWG    32     // workgroups per group (column slices)
#define CJ     32     // W_hh columns per WG
#define NVW    4      // vocab rows per WG (VOCAB/NWG)
#define NTHR   512

#define POISON 0x7F800000u   // (inf<<16): impossible for packed (bf16hi(tanh)<<16)|lo

// ws layout in float units
#define E2_OFF   0          // [128][1024] f32
#define WOT_OFF  131072     // [128][1024] bf16
#define BUF_OFF  196608     // [4][64][1024] u32 packed h

typedef __attribute__((ext_vector_type(8))) short short8_t;
typedef __attribute__((ext_vector_type(4))) float f32x4;

// ---------------- coherent (cross-XCD, MALL-level) access helpers ----------------
__device__ __forceinline__ uint4 cload4u(const void* p) {
    uint4 v;
    asm volatile("global_load_dwordx4 %0, %1, off sc0 sc1" : "=v"(v) : "v"(p));
    return v;
}
__device__ __forceinline__ void cstoreu(unsigned int* p, unsigned int x) {
    asm volatile("global_store_dword %0, %1, off sc0 sc1" :: "v"(p), "v"(x) : "memory");
}
// rule-18: every WAITVM0 ordering asm-load RESULTS against register-only code
// must be followed by sched_barrier(0).
#define WAITVM0() asm volatile("s_waitcnt vmcnt(0)" ::: "memory")
#define SCHED_FENCE() __builtin_amdgcn_sched_barrier(0)

// ---------------- bf16 helpers ----------------
__device__ __forceinline__ unsigned short bf16_rne(float f) {
    unsigned int u = __float_as_uint(f);
    u += 0x7FFF + ((u >> 16) & 1);
    return (unsigned short)(u >> 16);
}
__device__ __forceinline__ float bf16_f32(unsigned short h) {
    return __uint_as_float(((unsigned int)h) << 16);
}
__device__ __forceinline__ bool ok8(const uint4 a, const uint4 b) {
    return a.x != POISON && a.y != POISON && a.z != POISON && a.w != POISON
        && b.x != POISON && b.y != POISON && b.z != POISON && b.w != POISON;
}
__device__ __forceinline__ void unpack8(const uint4 a, const uint4 b,
                                        short8_t* h8, short8_t* l8) {
    (*h8)[0]=(short)(a.x>>16); (*l8)[0]=(short)(a.x&0xFFFF);
    (*h8)[1]=(short)(a.y>>16); (*l8)[1]=(short)(a.y&0xFFFF);
    (*h8)[2]=(short)(a.z>>16); (*l8)[2]=(short)(a.z&0xFFFF);
    (*h8)[3]=(short)(a.w>>16); (*l8)[3]=(short)(a.w&0xFFFF);
    (*h8)[4]=(short)(b.x>>16); (*l8)[4]=(short)(b.x&0xFFFF);
    (*h8)[5]=(short)(b.y>>16); (*l8)[5]=(short)(b.y&0xFFFF);
    (*h8)[6]=(short)(b.z>>16); (*l8)[6]=(short)(b.z&0xFFFF);
    (*h8)[7]=(short)(b.w>>16); (*l8)[7]=(short)(b.w&0xFFFF);
}

// ---------------- E2 = emb @ W_hx + b_hx  ([128][1024] f32) ----------------
__global__ void e2_kernel(const float* __restrict__ emb, const float* __restrict__ W_hx,
                          const float* __restrict__ b_hx, float* __restrict__ E2) {
    int v = blockIdx.x >> 2;
    int j = (blockIdx.x & 3) * 256 + threadIdx.x;
    const float* er = emb + (size_t)v * HIDDEN;
    float acc = 0.f;
#pragma unroll 8
    for (int k = 0; k < HIDDEN; ++k)
        acc += er[k] * W_hx[(size_t)k * HIDDEN + j];
    E2[(size_t)v * HIDDEN + j] = acc + b_hx[j];
}

// ---------------- WoT[v][k] = bf16(W_out[k][v]) ----------------
__global__ void wot_kernel(const float* __restrict__ W_out, unsigned short* __restrict__ WoT) {
    int v  = blockIdx.x;
    int k4 = threadIdx.x;
    ushort4 r;
    r.x = bf16_rne(W_out[(size_t)(k4*4+0)*VOCAB + v]);
    r.y = bf16_rne(W_out[(size_t)(k4*4+1)*VOCAB + v]);
    r.z = bf16_rne(W_out[(size_t)(k4*4+2)*VOCAB + v]);
    r.w = bf16_rne(W_out[(size_t)(k4*4+3)*VOCAB + v]);
    ((ushort4*)(WoT + (size_t)v * HIDDEN))[k4] = r;
}

// ---------------- poison init (graph-replay deterministic) ----------------
__global__ void poison_kernel(unsigned int* __restrict__ bufs) {
    int i = blockIdx.x * 256 + threadIdx.x;
    ((uint4*)bufs)[i] = make_uint4(POISON, POISON, POISON, POISON);
}

// ---------------- persistent recurrence kernel ----------------
// grid = 128 blocks (4 groups x 32 col-slices), 512 threads (8 waves), 80KB LDS.
// Sliced exchange: each wave polls ONLY its k-window (its 4 producer WGs),
// A-fragments go register-direct to MFMA (no LDS round trip). 3 barriers/step.
extern "C" __global__ void __launch_bounds__(NTHR, 2)
rnn_kernel(const int* __restrict__ x, const float* __restrict__ h0,
           const float* __restrict__ W_hh,
           const float* __restrict__ E2, const unsigned short* __restrict__ WoT,
           const float* __restrict__ b_out,
           unsigned int* __restrict__ bufs,
           float* __restrict__ logits, float* __restrict__ hf) {
    extern __shared__ char lds_raw[];
    short* sHi  = (short*)lds_raw;                 // [16][1024] bf16 hi, chunk-swizzled: 32KB
    float* sPart = (float*)(lds_raw + 32768);      // [8][512] f32: 16KB (logits reuse [8][64])
    int*   sX   = (int*)(lds_raw + 49152);         // [16][512] int: 32KB

    const int wg = blockIdx.x;
    const int g  = wg / NWG;
    const int w  = wg % NWG;
    const int b0 = g * BG;
    const int j0 = w * CJ;
    const int tid  = threadIdx.x;
    const int lane = tid & 63;
    const int wv   = tid >> 6;
    const int r    = lane & 15;       // A-frag row (batch) / C col
    const int kg   = lane >> 4;       // A-frag k-subgroup / C row-group

    // ---- prologue: x slice -> LDS ----
    {
        const int4* xs4 = (const int4*)(x + (size_t)b0 * SEQ);
#pragma unroll
        for (int i = 0; i < 4; ++i)
            ((int4*)sX)[tid + 512 * i] = xs4[tid + 512 * i];
    }

    // ---- prologue: W_hh column slice -> bf16 hi/lo fragments in VGPRs ----
    // wave wv owns k in [wv*128, wv*128+128); B-frag: lane l holds B[k=(l>>4)*8+e][col=l&15]
    short8_t whi[2][4], wlo[2][4];
    {
#pragma unroll
        for (int ct = 0; ct < 2; ++ct) {
            int col = j0 + ct * 16 + r;
#pragma unroll
            for (int c = 0; c < 4; ++c) {
                int kb = wv * 128 + c * 32 + kg * 8;
#pragma unroll
                for (int e = 0; e < 8; ++e) {
                    float wval = W_hh[(size_t)(kb + e) * HIDDEN + col];
                    unsigned short hi = bf16_rne(wval);
                    whi[ct][c][e] = (short)hi;
                    wlo[ct][c][e] = (short)bf16_rne(wval - bf16_f32(hi));
                }
            }
        }
    }

    // ---- prologue: W_out slice (NVW=4 vocab rows) -> bf16 B-frags (cols 4..15 zero) ----
    short8_t wvo[4];
    {
#pragma unroll
        for (int c = 0; c < 4; ++c) {
            int kb = wv * 128 + c * 32 + kg * 8;
#pragma unroll
            for (int e = 0; e < 8; ++e)
                wvo[c][e] = (r < NVW)
                    ? (short)WoT[(size_t)(w * NVW + r) * HIDDEN + kb + e] : (short)0;
        }
    }
    const float boV = (tid < 64) ? b_out[w * NVW + (tid & 3)] : 0.f;
    const int rb = tid >> 5, jb = tid & 31;     // finish mapping: batch, col
    __syncthreads();

    for (int t = 0; t < SEQ; ++t) {
        float e2p = E2[(size_t)sX[rb * SEQ + t] * HIDDEN + j0 + jb];

        // ---- acquire this wave's A-slice (row r, k-window [wv*128,+128)) into regs ----
        short8_t ahi[4], alo[4];
        if (t == 0) {
            const float* hr = h0 + ((size_t)(b0 + r) << 10) + wv * 128 + kg * 8;
#pragma unroll
            for (int c = 0; c < 4; ++c) {
                float4 f0 = *(const float4*)(hr + c * 32);
                float4 f1 = *(const float4*)(hr + c * 32 + 4);
                float fv[8] = {f0.x,f0.y,f0.z,f0.w,f1.x,f1.y,f1.z,f1.w};
#pragma unroll
                for (int e = 0; e < 8; ++e) {
                    unsigned short hi = bf16_rne(fv[e]);
                    ahi[c][e] = (short)hi;
                    alo[c][e] = (short)bf16_rne(fv[e] - bf16_f32(hi));
                }
            }
        } else {
            const unsigned int* src = bufs + ((size_t)((t - 1) & 3) << 16)
                                           + ((size_t)(b0 + r) << 10) + wv * 128 + kg * 8;
            uint4 d0a,d0b,d1a,d1b,d2a,d2b,d3a,d3b;
            unsigned pend = 0xF;
            int guard = 0;
            do {
                if (pend & 1u) { d0a = cload4u(src +  0); d0b = cload4u(src +  4); }
                if (pend & 2u) { d1a = cload4u(src + 32); d1b = cload4u(src + 36); }
                if (pend & 4u) { d2a = cload4u(src + 64); d2b = cload4u(src + 68); }
                if (pend & 8u) { d3a = cload4u(src + 96); d3b = cload4u(src + 100); }
                WAITVM0();
                SCHED_FENCE();   // rule 18: checks AFTER the hardware wait
                if ((pend & 1u) && ok8(d0a, d0b)) pend &= ~1u;
                if ((pend & 2u) && ok8(d1a, d1b)) pend &= ~2u;
                if ((pend & 4u) && ok8(d2a, d2b)) pend &= ~4u;
                if ((pend & 8u) && ok8(d3a, d3b)) pend &= ~8u;
                if (!pend) break;
                __builtin_amdgcn_s_sleep(1);
            } while (++guard < (1 << 20));
            SCHED_FENCE();
            unpack8(d0a, d0b, &ahi[0], &alo[0]);
            unpack8(d1a, d1b, &ahi[1], &alo[1]);
            unpack8(d2a, d2b, &ahi[2], &alo[2]);
            unpack8(d3a, d3b, &ahi[3], &alo[3]);
        }

        // ---- publish hi slice to LDS for the logits phase (own chunks only) ----
#pragma unroll
        for (int c = 0; c < 4; ++c) {
            int c8 = wv * 16 + c * 4 + kg;
            *(short8_t*)(sHi + r * 1024 + ((c8 ^ (r & 7)) << 3)) = ahi[c];
        }

        // ---- main MFMA: C[16b x 32j] += h[16 x 128k] * W[128k x 32j], A from regs ----
        f32x4 acc0 = {0.f, 0.f, 0.f, 0.f};
        f32x4 acc1 = {0.f, 0.f, 0.f, 0.f};
#pragma unroll
        for (int c = 0; c < 4; ++c) {
            acc0 = __builtin_amdgcn_mfma_f32_16x16x32_bf16(ahi[c], whi[0][c], acc0, 0, 0, 0);
            acc1 = __builtin_amdgcn_mfma_f32_16x16x32_bf16(ahi[c], whi[1][c], acc1, 0, 0, 0);
            acc0 = __builtin_amdgcn_mfma_f32_16x16x32_bf16(alo[c], whi[0][c], acc0, 0, 0, 0);
            acc1 = __builtin_amdgcn_mfma_f32_16x16x32_bf16(alo[c], whi[1][c], acc1, 0, 0, 0);
            acc0 = __builtin_amdgcn_mfma_f32_16x16x32_bf16(ahi[c], wlo[0][c], acc0, 0, 0, 0);
            acc1 = __builtin_amdgcn_mfma_f32_16x16x32_bf16(ahi[c], wlo[1][c], acc1, 0, 0, 0);
        }
        // C layout: col=lane&15, row=(lane>>4)*4+q -> sPart[wv][row][col(+16*ct)]
#pragma unroll
        for (int q = 0; q < 4; ++q) {
            sPart[wv * 512 + (kg * 4 + q) * 32 + r]      = acc0[q];
            sPart[wv * 512 + (kg * 4 + q) * 32 + 16 + r] = acc1[q];
        }
        __syncthreads();   // (b): sPart + sHi complete

        // ---- finish: reduce 8 partials + E2 + tanh; fire-and-forget packed store ----
        {
            float s = 0.f;
#pragma unroll
            for (int z = 0; z < 8; ++z) s += sPart[z * 512 + tid];
            float hn = tanhf(s + e2p);
            unsigned short hi = bf16_rne(hn);
            unsigned short lo = bf16_rne(hn - bf16_f32(hi));
            unsigned int pk = ((unsigned int)hi << 16) | (unsigned int)lo;
            size_t idx = ((size_t)(b0 + rb) << 10) + j0 + jb;
            cstoreu(bufs + ((size_t)(t & 3) << 16) + idx, pk);             // data
            cstoreu(bufs + ((size_t)((t + 2) & 3) << 16) + idx, POISON);   // re-arm
            if (t == SEQ - 1)
                hf[(size_t)(b0 + rb) * HIDDEN + j0 + jb] = hn;
        }
        __syncthreads();   // (c): sPart reads done -> logits may overwrite

        // ---- distributed logits for position t-1 via MFMA (4 vocab cols, 12 padded) ----
        if (t > 0) {
            f32x4 accL = {0.f, 0.f, 0.f, 0.f};
#pragma unroll
            for (int c = 0; c < 4; ++c) {
                int c8 = wv * 16 + c * 4 + kg;
                short8_t a8 = *(const short8_t*)(sHi + r * 1024 + ((c8 ^ (r & 7)) << 3));
                accL = __builtin_amdgcn_mfma_f32_16x16x32_bf16(a8, wvo[c], accL, 0, 0, 0);
            }
            if (r < NVW) {
#pragma unroll
                for (int q = 0; q < 4; ++q)
                    sPart[wv * 64 + (kg * 4 + q) * 4 + r] = accL[q];
            }
            __syncthreads();   // (d)
            if (tid < 64) {
                int b = tid >> 2, v = tid & 3;
                float s = 0.f;
#pragma unroll
                for (int z = 0; z < 8; ++z) s += sPart[z * 64 + b * 4 + v];
                logits[((size_t)(b0 + b) * SEQ + (t - 1)) * VOCAB + w * NVW + v] = s + boV;
            }
        }
    }

    // ---- epilogue: logits for position SEQ-1 from h_SEQ (buf[3], hi only) ----
    {
        const unsigned int* src = bufs + ((size_t)((SEQ - 1) & 3) << 16)
                                       + ((size_t)(b0 + r) << 10) + wv * 128 + kg * 8;
        uint4 d0a,d0b,d1a,d1b,d2a,d2b,d3a,d3b;
        unsigned pend = 0xF;
        int guard = 0;
        do {
            if (pend & 1u) { d0a = cload4u(src +  0); d0b = cload4u(src +  4); }
            if (pend & 2u) { d1a = cload4u(src + 32); d1b = cload4u(src + 36); }
            if (pend & 4u) { d2a = cload4u(src + 64); d2b = cload4u(src + 68); }
            if (pend & 8u) { d3a = cload4u(src + 96); d3b = cload4u(src + 100); }
            WAITVM0();
            SCHED_FENCE();
            if ((pend & 1u) && ok8(d0a, d0b)) pend &= ~1u;
            if ((pend & 2u) && ok8(d1a, d1b)) pend &= ~2u;
            if ((pend & 4u) && ok8(d2a, d2b)) pend &= ~4u;
            if ((pend & 8u) && ok8(d3a, d3b)) pend &= ~8u;
            if (!pend) break;
            __builtin_amdgcn_s_sleep(1);
        } while (++guard < (1 << 20));
        SCHED_FENCE();
        short8_t h8, l8;
        unpack8(d0a, d0b, &h8, &l8);
        *(short8_t*)(sHi + r * 1024 + (((wv * 16 + 0 * 4 + kg) ^ (r & 7)) << 3)) = h8;
        unpack8(d1a, d1b, &h8, &l8);
        *(short8_t*)(sHi + r * 1024 + (((wv * 16 + 1 * 4 + kg) ^ (r & 7)) << 3)) = h8;
        unpack8(d2a, d2b, &h8, &l8);
        *(short8_t*)(sHi + r * 1024 + (((wv * 16 + 2 * 4 + kg) ^ (r & 7)) << 3)) = h8;
        unpack8(d3a, d3b, &h8, &l8);
        *(short8_t*)(sHi + r * 1024 + (((wv * 16 + 3 * 4 + kg) ^ (r & 7)) << 3)) = h8;
    }
    __syncthreads();
    {
        f32x4 accL = {0.f, 0.f, 0.f, 0.f};
#pragma unroll
        for (int c = 0; c < 4; ++c) {
            int c8 = wv * 16 + c * 4 + kg;
            short8_t a8 = *(const short8_t*)(sHi + r * 1024 + ((c8 ^ (r & 7)) << 3));
            accL = __builtin_amdgcn_mfma_f32_16x16x32_bf16(a8, wvo[c], accL, 0, 0, 0);
        }
        if (r < NVW) {
#pragma unroll
            for (int q = 0; q < 4; ++q)
                sPart[wv * 64 + (kg * 4 + q) * 4 + r] = accL[q];
        }
        __syncthreads();
        if (tid < 64) {
            int b = tid >> 2, v = tid & 3;
            float s = 0.f;
#pragma unroll
            for (int z = 0; z < 8; ++z) s += sPart[z * 64 + b * 4 + v];
            logits[((size_t)(b0 + b) * SEQ + (SEQ - 1)) * VOCAB + w * NVW + v] = s + boV;
        }
    }
}

extern "C" void kernel_launch(void* const* d_in, const int* in_sizes, int n_in,
                              void* d_out, int out_size, void* d_ws, size_t ws_size,
                              hipStream_t stream) {
    (void)in_sizes; (void)n_in; (void)out_size; (void)ws_size;
    const int*   x     = (const int*)  d_in[0];
    const float* h0    = (const float*)d_in[1];
    const float* emb   = (const float*)d_in[2];
    const float* W_hx  = (const float*)d_in[3];
    const float* b_hx  = (const float*)d_in[4];
    const float* W_hh  = (const float*)d_in[5];
    const float* W_out = (const float*)d_in[6];
    const float* b_out = (const float*)d_in[7];

    float* logits = (float*)d_out;
    float* hf     = logits + (size_t)BATCH * SEQ * VOCAB;

    float* ws  = (float*)d_ws;
    float* E2  = ws + E2_OFF;
    unsigned short* WoT = (unsigned short*)(ws + WOT_OFF);
    unsigned int*   bufs = (unsigned int*)(ws + BUF_OFF);

    poison_kernel<<<256, 256, 0, stream>>>(bufs);
    e2_kernel<<<512, 256, 0, stream>>>(emb, W_hx, b_hx, E2);
    wot_kernel<<<128, 256, 0, stream>>>(W_out, WoT);

    hipFuncSetAttribute(reinterpret_cast<const void*>(rnn_kernel),
                        hipFuncAttributeMaxDynamicSharedMemorySize, 81920);
    rnn_kernel<<<NGROUP * NWG, NTHR, 81920, stream>>>(x, h0, W_hh, E2, WoT, b_out,
                                                      bufs, logits, hf);
}